// Round 13
// baseline (588.481 us; speedup 1.0000x reference)
//
#include <hip/hip_runtime.h>
#include <hip/hip_bf16.h>
#include <math.h>

// Problem constants
constexpr int Bc = 4, Sc = 16, Pc = 256, Ec = 768, Hc = 12, HDc = 64, FFc = 3072;
constexpr int Mrows = Bc * Sc * Pc;              // 16384 token rows
constexpr size_t ME = (size_t)Mrows * Ec;        // 12,582,912 elements

typedef __attribute__((ext_vector_type(4))) float f32x4;
typedef __attribute__((ext_vector_type(8))) short s16x8;
typedef __attribute__((ext_vector_type(4))) short s16x4;

__device__ __forceinline__ short f2bf(float f) {
  union { float f; unsigned u; } v; v.f = f;
  unsigned r = (v.u + 0x7FFFu + ((v.u >> 16) & 1u)) >> 16;  // RNE
  return (short)r;
}
__device__ __forceinline__ float bf2f(short s) {
  union { unsigned u; float f; } v; v.u = ((unsigned)(unsigned short)s) << 16;
  return v.f;
}

// async global->LDS, 16B per lane; lds dest is wave-uniform base + lane*16.
// Source must be lane-contiguous (R9 lesson).
__device__ __forceinline__ void async16(const void* g, void* l) {
  __builtin_amdgcn_global_load_lds(
      (const __attribute__((address_space(1))) unsigned int*)g,
      (__attribute__((address_space(3))) unsigned int*)l, 16, 0, 0);
}

// ---------------------------------------------------------------------------
// Unified prep kernel: 6 weight transpose-converts + x->bf16, one dispatch.
// ---------------------------------------------------------------------------
__device__ __forceinline__ void wtrans_tile(const float* __restrict__ W,
                                            short* __restrict__ Wt,
                                            int K, int N, int n0, int k0, int t)
{
  const int n  = n0 + (t >> 2);
  const int kc = k0 + (t & 3) * 16;
  short buf[16];
#pragma unroll
  for (int i = 0; i < 16; ++i)
    buf[i] = f2bf(W[(size_t)(kc + i) * N + n]);
  *reinterpret_cast<s16x8*>(&Wt[(size_t)n * K + kc])     = *reinterpret_cast<s16x8*>(&buf[0]);
  *reinterpret_cast<s16x8*>(&Wt[(size_t)n * K + kc + 8]) = *reinterpret_cast<s16x8*>(&buf[8]);
}

__global__ __launch_bounds__(256)
void prep_kernel(const float* __restrict__ x, short* __restrict__ Xb,
                 const float* __restrict__ saqkv, short* __restrict__ wt_saqkv,
                 const float* __restrict__ sawo,  short* __restrict__ wt_sawo,
                 const float* __restrict__ taqkv, short* __restrict__ wt_taqkv,
                 const float* __restrict__ tawo,  short* __restrict__ wt_tawo,
                 const float* __restrict__ fw1,   short* __restrict__ wt_fw1,
                 const float* __restrict__ fw2,   short* __restrict__ wt_fw2)
{
  const int b = blockIdx.x;
  const int t = threadIdx.x;
  constexpr size_t EE = (size_t)Ec * Ec;

  if (b < 432) {
    const int z = b / 144, tl = b % 144;
    wtrans_tile(saqkv + (size_t)z * EE, wt_saqkv + (size_t)z * EE,
                Ec, Ec, (tl % 12) * 64, (tl / 12) * 64, t);
  } else if (b < 576) {
    const int tl = b - 432;
    wtrans_tile(sawo, wt_sawo, Ec, Ec, (tl % 12) * 64, (tl / 12) * 64, t);
  } else if (b < 1008) {
    const int z = (b - 576) / 144, tl = (b - 576) % 144;
    wtrans_tile(taqkv + (size_t)z * EE, wt_taqkv + (size_t)z * EE,
                Ec, Ec, (tl % 12) * 64, (tl / 12) * 64, t);
  } else if (b < 1152) {
    const int tl = b - 1008;
    wtrans_tile(tawo, wt_tawo, Ec, Ec, (tl % 12) * 64, (tl / 12) * 64, t);
  } else if (b < 1728) {
    const int tl = b - 1152;
    wtrans_tile(fw1, wt_fw1, Ec, FFc, (tl % 48) * 64, (tl / 48) * 64, t);
  } else if (b < 2304) {
    const int tl = b - 1728;
    wtrans_tile(fw2, wt_fw2, FFc, Ec, (tl % 12) * 64, (tl / 12) * 64, t);
  } else {
    const size_t i = (size_t)(b - 2304) * 256 + t;
    const float4* p = reinterpret_cast<const float4*>(x + i * 8);
    float4 a = p[0], bb = p[1];
    s16x8 o = { f2bf(a.x), f2bf(a.y), f2bf(a.z), f2bf(a.w),
                f2bf(bb.x), f2bf(bb.y), f2bf(bb.z), f2bf(bb.w) };
    *reinterpret_cast<s16x8*>(Xb + i * 8) = o;
  }
}

// ---------------------------------------------------------------------------
// Shared GEMM machinery. R13: 2 barriers/K-tile, compiler-scheduled interior.
// Per tile: read ALL frags (compiler emits counted lgkmcnt and interleaves
// MFMA under reads) -> stage A(t+1) to other slot -> lgkm(0)+barrier (all
// waves' reads RETURNED; required before same-slot B restage since a staged
// write may land any time after issue) -> stage B(t+2) -> MFMA burst ->
// counted vmcnt + barrier.
// ---------------------------------------------------------------------------
#define LDFRAG(base, row, kc) \
  (*reinterpret_cast<const s16x8*>((base) + (row) * 128 + ((((kc) ^ ((row) & 7)) << 4))))

#define TILE_SYNC_MID \
  do { \
    asm volatile("s_waitcnt lgkmcnt(0)" ::: "memory"); \
    __builtin_amdgcn_s_barrier(); \
    __builtin_amdgcn_sched_barrier(0); \
  } while (0)

#define TILE_END_VMC(cond, nstr) \
  do { \
    __builtin_amdgcn_s_setprio(0); \
    if (cond) asm volatile("s_waitcnt vmcnt(" nstr ")" ::: "memory"); \
    else      asm volatile("s_waitcnt vmcnt(0)" ::: "memory"); \
    __builtin_amdgcn_sched_barrier(0); \
    __builtin_amdgcn_s_barrier(); \
    __builtin_amdgcn_sched_barrier(0); \
  } while (0)

// ---------------------------------------------------------------------------
// GEMM 256x256 (BN=256), BK=64 — used for FF1. OUT: 1 = bf16 + relu.
// 8 waves (2M x 4N), per-wave 128x64, acc[8][4]; vmcnt(4) ring.
// ---------------------------------------------------------------------------
#define R256_READS(Aslot, Bslot) \
  do { \
    _Pragma("unroll") \
    for (int nj = 0; nj < 4; ++nj) { \
      bfr[nj][0] = LDFRAG((Bslot), wc * 64 + nj * 16 + l16, g); \
      bfr[nj][1] = LDFRAG((Bslot), wc * 64 + nj * 16 + l16, 4 + g); \
    } \
    _Pragma("unroll") \
    for (int mi = 0; mi < 8; ++mi) { \
      const int arow = wr * 128 + mi * 16 + l16; \
      afr[mi][0] = LDFRAG((Aslot), arow, g); \
      afr[mi][1] = LDFRAG((Aslot), arow, 4 + g); \
    } \
  } while (0)

#define R256_MMA_ALL \
  do { \
    __builtin_amdgcn_s_setprio(1); \
    _Pragma("unroll") \
    for (int mi = 0; mi < 8; ++mi) \
      _Pragma("unroll") \
      for (int nj = 0; nj < 4; ++nj) { \
        acc[mi][nj] = __builtin_amdgcn_mfma_f32_16x16x32_bf16( \
            afr[mi][0], bfr[nj][0], acc[mi][nj], 0, 0, 0); \
        acc[mi][nj] = __builtin_amdgcn_mfma_f32_16x16x32_bf16( \
            afr[mi][1], bfr[nj][1], acc[mi][nj], 0, 0, 0); \
      } \
  } while (0)

template<int OUT>
__global__ __launch_bounds__(512, 2)
void gemm256_kernel(const short* __restrict__ A, const short* __restrict__ Wt,
                    const float* __restrict__ biasg, const void* __restrict__ resv,
                    void* __restrict__ Cg, short* __restrict__ vt,
                    int M, int N, int K)
{
  __shared__ char smem[131072];
  const int z = blockIdx.z;
  const short* __restrict__ Wz = Wt + (size_t)z * (size_t)N * K;
  const float* __restrict__ bz = biasg + (size_t)z * N;

  const int nwg = gridDim.x;
  const int swz = ((int)blockIdx.x & 7) * (nwg >> 3) + ((int)blockIdx.x >> 3);
  const int NT = N >> 8;
  const int bm = (swz / NT) << 8;
  const int bn = (swz % NT) << 8;

  const int tid  = threadIdx.x;
  const int lane = tid & 63;
  const int wid  = tid >> 6;
  const int wr   = wid >> 2;
  const int wc   = wid & 3;
  const int l16  = lane & 15;
  const int g    = lane >> 4;

  char* const As0 = smem;
  char* const Bs0 = smem + 32768;
  char* const As1 = smem + 65536;
  char* const Bs1 = smem + 98304;

  const int srow = lane >> 3;
  const int scol = ((lane & 7) ^ srow) * 8;
  const int ldso = wid * 1024;

  auto stageG = [&](const short* __restrict__ G, int grow0, int k0, char* ldsHalf) {
    const size_t r0 = (size_t)(grow0 + wid * 8 + srow);
    async16(G + r0 * K + (k0 + scol), ldsHalf + ldso);
    async16(G + (r0 + 64) * K + (k0 + scol), ldsHalf + 8192 + ldso);
  };

  f32x4 acc[8][4];
  s16x8 afr[8][2];
  s16x8 bfr[4][2];
#pragma unroll
  for (int mi = 0; mi < 8; ++mi)
#pragma unroll
    for (int nj = 0; nj < 4; ++nj) acc[mi][nj] = f32x4{0.f, 0.f, 0.f, 0.f};

  const int ntile = K >> 6;
  const int nit   = ntile >> 1;

  stageG(A,  bm,        0,  As0);
  stageG(A,  bm + 128,  0,  As0 + 16384);
  stageG(Wz, bn,        0,  Bs0);
  stageG(Wz, bn + 128,  0,  Bs0 + 16384);
  stageG(Wz, bn,        64, Bs1);
  stageG(Wz, bn + 128,  64, Bs1 + 16384);
  asm volatile("s_waitcnt vmcnt(4)" ::: "memory");
  __builtin_amdgcn_sched_barrier(0);
  __builtin_amdgcn_s_barrier();

  for (int j = 0; j < nit; ++j) {
    const int t1k = (2 * j + 1) << 6;
    const int t2k = (2 * j + 2) << 6;
    const int t3k = (2 * j + 3) << 6;
    const bool s2 = (2 * j + 2) < ntile;
    const bool s3 = (2 * j + 3) < ntile;

    // ---- tile 2j (As0/Bs0) ----
    R256_READS(As0, Bs0);
    stageG(A, bm,       t1k, As1);
    stageG(A, bm + 128, t1k, As1 + 16384);
    TILE_SYNC_MID;                        // all waves' reads returned
    if (s2) { stageG(Wz, bn, t2k, Bs0); stageG(Wz, bn + 128, t2k, Bs0 + 16384); }
    R256_MMA_ALL;
    TILE_END_VMC(s2, "4");                // forces A(t1),B(t1) landed

    // ---- tile 2j+1 (As1/Bs1) ----
    R256_READS(As1, Bs1);
    if (s2) { stageG(A, bm, t2k, As0); stageG(A, bm + 128, t2k, As0 + 16384); }
    TILE_SYNC_MID;
    if (s3) { stageG(Wz, bn, t3k, Bs1); stageG(Wz, bn + 128, t3k, Bs1 + 16384); }
    R256_MMA_ALL;
    TILE_END_VMC(s3, "4");                // forces B(t2),A(t2) landed
  }

  short* Cb = (short*)Cg + (size_t)z * (size_t)M * N;
#pragma unroll
  for (int mi = 0; mi < 8; ++mi) {
    const int row0 = bm + wr * 128 + mi * 16 + g * 4;
#pragma unroll
    for (int nj = 0; nj < 4; ++nj) {
      const int col = bn + wc * 64 + nj * 16 + l16;
      const float bias = bz[col];
#pragma unroll
      for (int r = 0; r < 4; ++r) {
        float v = acc[mi][nj][r] + bias;
        size_t idx = (size_t)(row0 + r) * N + col;
        if (OUT == 1) v = fmaxf(v, 0.f);
        Cb[idx] = f2bf(v);
      }
    }
  }
}

// ---------------------------------------------------------------------------
// GEMM 256x192 (BN=192), BK=64 — N=768 family. Per-wave 128x48, acc[8][3].
// vmcnt ring: 7 loads/tile (A:4, B:3) -> vmcnt(3) at each tile end.
// OUT: 0 bf16 | 3 bf16 + bf16 residual | 4 QKV-A (z==2 -> transposed-V)
// ---------------------------------------------------------------------------
#define R192_READS(Aslot, Bslot) \
  do { \
    _Pragma("unroll") \
    for (int nj = 0; nj < 3; ++nj) { \
      const int brow = wc * 48 + nj * 16 + l16; \
      bfr[nj][0] = LDFRAG((Bslot), brow, g); \
      bfr[nj][1] = LDFRAG((Bslot), brow, 4 + g); \
    } \
    _Pragma("unroll") \
    for (int mi = 0; mi < 8; ++mi) { \
      const int arow = wr * 128 + mi * 16 + l16; \
      afr[mi][0] = LDFRAG((Aslot), arow, g); \
      afr[mi][1] = LDFRAG((Aslot), arow, 4 + g); \
    } \
  } while (0)

#define R192_MMA_ALL \
  do { \
    __builtin_amdgcn_s_setprio(1); \
    _Pragma("unroll") \
    for (int mi = 0; mi < 8; ++mi) \
      _Pragma("unroll") \
      for (int nj = 0; nj < 3; ++nj) { \
        acc[mi][nj] = __builtin_amdgcn_mfma_f32_16x16x32_bf16( \
            afr[mi][0], bfr[nj][0], acc[mi][nj], 0, 0, 0); \
        acc[mi][nj] = __builtin_amdgcn_mfma_f32_16x16x32_bf16( \
            afr[mi][1], bfr[nj][1], acc[mi][nj], 0, 0, 0); \
      } \
  } while (0)

template<int OUT>
__global__ __launch_bounds__(512, 2)
void gemm192_kernel(const short* __restrict__ A, const short* __restrict__ Wt,
                    const float* __restrict__ biasg, const void* __restrict__ resv,
                    void* __restrict__ Cg, short* __restrict__ vt,
                    int M, int N, int K)
{
  __shared__ char smem[114688];   // As0 32K | As1 32K | Bs0 24K | Bs1 24K
  const int z = blockIdx.z;
  const short* __restrict__ Wz = Wt + (size_t)z * (size_t)N * K;
  const float* __restrict__ bz = biasg + (size_t)z * N;

  const int nwg = gridDim.x;
  const int swz = ((int)blockIdx.x & 7) * (nwg >> 3) + ((int)blockIdx.x >> 3);
  const int NT = N / 192;
  const int bm = (swz / NT) << 8;
  const int bn = (swz % NT) * 192;

  const int tid  = threadIdx.x;
  const int lane = tid & 63;
  const int wid  = tid >> 6;
  const int wr   = wid >> 2;
  const int wc   = wid & 3;
  const int l16  = lane & 15;
  const int g    = lane >> 4;

  char* const As0 = smem;
  char* const As1 = smem + 32768;
  char* const Bs0 = smem + 65536;
  char* const Bs1 = smem + 90112;

  const int srow = lane >> 3;
  const int scol = ((lane & 7) ^ srow) * 8;
  const int ldso = wid * 1024;

  auto stageG = [&](const short* __restrict__ G, int grow0, int k0, char* ldsHalf) {
    const size_t r0 = (size_t)(grow0 + wid * 8 + srow);
    async16(G + r0 * K + (k0 + scol), ldsHalf + ldso);
    async16(G + (r0 + 64) * K + (k0 + scol), ldsHalf + 8192 + ldso);
  };
  auto stageB = [&](const short* __restrict__ G, int grow0, int k0, char* ldsB) {
    const size_t r0 = (size_t)(grow0 + wid * 8 + srow);
    async16(G + r0 * K + (k0 + scol), ldsB + ldso);
    async16(G + (r0 + 64) * K + (k0 + scol), ldsB + 8192 + ldso);
    async16(G + (r0 + 128) * K + (k0 + scol), ldsB + 16384 + ldso);
  };

  f32x4 acc[8][3];
  s16x8 afr[8][2];
  s16x8 bfr[3][2];
#pragma unroll
  for (int mi = 0; mi < 8; ++mi)
#pragma unroll
    for (int nj = 0; nj < 3; ++nj) acc[mi][nj] = f32x4{0.f, 0.f, 0.f, 0.f};

  const int ntile = K >> 6;
  const int nit   = ntile >> 1;

  stageG(A,  bm,       0,  As0);
  stageG(A,  bm + 128, 0,  As0 + 16384);
  stageB(Wz, bn,       0,  Bs0);
  stageB(Wz, bn,       64, Bs1);
  asm volatile("s_waitcnt vmcnt(3)" ::: "memory");
  __builtin_amdgcn_sched_barrier(0);
  __builtin_amdgcn_s_barrier();

  for (int j = 0; j < nit; ++j) {
    const int t1k = (2 * j + 1) << 6;
    const int t2k = (2 * j + 2) << 6;
    const int t3k = (2 * j + 3) << 6;
    const bool s2 = (2 * j + 2) < ntile;
    const bool s3 = (2 * j + 3) < ntile;

    // ---- tile 2j (As0/Bs0) ----
    R192_READS(As0, Bs0);
    stageG(A, bm,       t1k, As1);
    stageG(A, bm + 128, t1k, As1 + 16384);
    TILE_SYNC_MID;                        // all waves' reads returned
    if (s2) stageB(Wz, bn, t2k, Bs0);
    R192_MMA_ALL;
    TILE_END_VMC(s2, "3");                // forces A(t1),B(t1) landed

    // ---- tile 2j+1 (As1/Bs1) ----
    R192_READS(As1, Bs1);
    if (s2) { stageG(A, bm, t2k, As0); stageG(A, bm + 128, t2k, As0 + 16384); }
    TILE_SYNC_MID;
    if (s3) stageB(Wz, bn, t3k, Bs1);
    R192_MMA_ALL;
    TILE_END_VMC(s3, "3");                // forces A(t2),B(t2) landed
  }

  const short* resb = (const short*)resv;
  short* Cb = (short*)Cg + (size_t)z * (size_t)M * N;

#pragma unroll
  for (int mi = 0; mi < 8; ++mi) {
    const int row0 = bm + wr * 128 + mi * 16 + g * 4;
#pragma unroll
    for (int nj = 0; nj < 3; ++nj) {
      const int col = bn + wc * 48 + nj * 16 + l16;
      if (OUT == 4 && z == 2) {
        const int bs2 = row0 >> 8, p0 = row0 & 255;
        const int h2 = col >> 6,  d2 = col & 63;
        const float bias = bz[col];
        s16x4 v = { f2bf(acc[mi][nj][0] + bias), f2bf(acc[mi][nj][1] + bias),
                    f2bf(acc[mi][nj][2] + bias), f2bf(acc[mi][nj][3] + bias) };
        *reinterpret_cast<s16x4*>(
            &vt[(((size_t)bs2 * 12 + h2) * 64 + d2) * 256 + p0]) = v;
      } else {
        const float bias = bz[col];
#pragma unroll
        for (int r = 0; r < 4; ++r) {
          float v = acc[mi][nj][r] + bias;
          size_t idx = (size_t)(row0 + r) * N + col;
          if (OUT == 3) v += bf2f(resb[idx]);
          Cb[idx] = f2bf(v);
        }
      }
    }
  }
}

// ---------------------------------------------------------------------------
// Spatial attention, MFMA flash, barrier-free (unchanged).
// ---------------------------------------------------------------------------
__global__ __launch_bounds__(256, 3)
void spatial_attn_kernel(const short* __restrict__ Qg, const short* __restrict__ Kg,
                         const short* __restrict__ Vt, short* __restrict__ Og)
{
  const int bs = blockIdx.x;
  const int h  = blockIdx.y;

  __shared__ short Pl[4 * 32 * 64];

  const int tid  = threadIdx.x;
  const int lane = tid & 63;
  const int wid  = tid >> 6;
  const int l16  = lane & 15;
  const int g    = lane >> 4;
  const int q0   = blockIdx.z * 128 + wid * 32;
  char* Pw = (char*)Pl + wid * 4096;

  const size_t rowbase = (size_t)(bs * 256) * 768 + h * 64;
  const size_t vbase   = ((size_t)bs * 12 + h) * 64 * 256;

  s16x8 qa[2][2];
#pragma unroll
  for (int m = 0; m < 2; ++m)
#pragma unroll
    for (int ks = 0; ks < 2; ++ks)
      qa[m][ks] = *reinterpret_cast<const s16x8*>(
          &Qg[rowbase + (size_t)(q0 + m * 16 + l16) * 768 + ks * 32 + g * 8]);

  float mrun[2][4], lrun[2][4];
  f32x4 oac[2][4];
#pragma unroll
  for (int m = 0; m < 2; ++m)
#pragma unroll
    for (int r = 0; r < 4; ++r) { mrun[m][r] = -INFINITY; lrun[m][r] = 0.f; }
#pragma unroll
  for (int m = 0; m < 2; ++m)
#pragma unroll
    for (int n = 0; n < 4; ++n) oac[m][n] = f32x4{0.f, 0.f, 0.f, 0.f};

#pragma unroll
  for (int t = 0; t < 4; ++t) {
    const int key0 = t * 64;
    f32x4 sc[2][4];
#pragma unroll
    for (int m = 0; m < 2; ++m)
#pragma unroll
      for (int n = 0; n < 4; ++n) sc[m][n] = f32x4{0.f, 0.f, 0.f, 0.f};
#pragma unroll
    for (int ks = 0; ks < 2; ++ks) {
      s16x8 kf[4];
#pragma unroll
      for (int n = 0; n < 4; ++n) {
        const int key = key0 + n * 16 + l16;
        kf[n] = *reinterpret_cast<const s16x8*>(
            &Kg[rowbase + (size_t)key * 768 + ks * 32 + g * 8]);
      }
#pragma unroll
      for (int m = 0; m < 2; ++m)
#pragma unroll
        for (int n = 0; n < 4; ++n)
          sc[m][n] = __builtin_amdgcn_mfma_f32_16x16x32_bf16(qa[m][ks], kf[n], sc[m][n], 0, 0, 0);
    }
#pragma unroll
    for (int m = 0; m < 2; ++m)
#pragma unroll
      for (int n = 0; n < 4; ++n)
#pragma unroll
        for (int r = 0; r < 4; ++r) sc[m][n][r] *= 0.125f;

#pragma unroll
    for (int m = 0; m < 2; ++m) {
#pragma unroll
      for (int r = 0; r < 4; ++r) {
        float mx = fmaxf(fmaxf(sc[m][0][r], sc[m][1][r]), fmaxf(sc[m][2][r], sc[m][3][r]));
#pragma unroll
        for (int mk = 1; mk < 16; mk <<= 1) mx = fmaxf(mx, __shfl_xor(mx, mk, 64));
        const float mnew = fmaxf(mrun[m][r], mx);
        const float corr = __expf(mrun[m][r] - mnew);
        mrun[m][r] = mnew;
        float rs = 0.f;
#pragma unroll
        for (int n = 0; n < 4; ++n) {
          float p = __expf(sc[m][n][r] - mnew);
          sc[m][n][r] = p;
          rs += p;
        }
#pragma unroll
        for (int mk = 1; mk < 16; mk <<= 1) rs += __shfl_xor(rs, mk, 64);
        lrun[m][r] = lrun[m][r] * corr + rs;
#pragma unroll
        for (int nd = 0; nd < 4; ++nd) oac[m][nd][r] *= corr;
      }
    }
#pragma unroll
    for (int m = 0; m < 2; ++m)
#pragma unroll
      for (int n = 0; n < 4; ++n)
#pragma unroll
        for (int r = 0; r < 4; ++r) {
          const int q = m * 16 + g * 4 + r;
          const int key = n * 16 + l16;
          const int byte = q * 128 + (((key >> 3) ^ (q & 7)) * 16) + (key & 7) * 2;
          *reinterpret_cast<short*>(Pw + byte) = f2bf(sc[m][n][r]);
        }
#pragma unroll
    for (int ks = 0; ks < 2; ++ks) {
      s16x8 pa[2], vf[4];
#pragma unroll
      for (int m = 0; m < 2; ++m) {
        const int q = m * 16 + l16;
        const int s = ks * 4 + g;
        pa[m] = *reinterpret_cast<const s16x8*>(Pw + q * 128 + ((s ^ (q & 7)) * 16));
      }
#pragma unroll
      for (int nd = 0; nd < 4; ++nd) {
        const int d = nd * 16 + l16;
        const int key = key0 + ks * 32 + g * 8;
        vf[nd] = *reinterpret_cast<const s16x8*>(&Vt[vbase + (size_t)d * 256 + key]);
      }
#pragma unroll
      for (int m = 0; m < 2; ++m)
#pragma unroll
        for (int nd = 0; nd < 4; ++nd)
          oac[m][nd] = __builtin_amdgcn_mfma_f32_16x16x32_bf16(pa[m], vf[nd], oac[m][nd], 0, 0, 0);
    }
  }

#pragma unroll
  for (int m = 0; m < 2; ++m)
#pragma unroll
    for (int r = 0; r < 4; ++r) {
      const float inv = 1.f / lrun[m][r];
#pragma unroll
      for (int nd = 0; nd < 4; ++nd) oac[m][nd][r] *= inv;
    }
#pragma unroll
  for (int m = 0; m < 2; ++m)
#pragma unroll
    for (int nd = 0; nd < 4; ++nd)
#pragma unroll
      for (int r = 0; r < 4; ++r) {
        const int q = m * 16 + g * 4 + r;
        const int d = nd * 16 + l16;
        const int byte = q * 128 + (((d >> 3) ^ (q & 7)) * 16) + (d & 7) * 2;
        *reinterpret_cast<short*>(Pw + byte) = f2bf(oac[m][nd][r]);
      }
#pragma unroll
  for (int it = 0; it < 4; ++it) {
    const int slot = it * 64 + lane;
    const int q = slot >> 3, sl = slot & 7;
    const int d0 = (sl ^ (q & 7)) * 8;
    s16x8 v = *reinterpret_cast<const s16x8*>(Pw + slot * 16);
    *reinterpret_cast<s16x8*>(
        &Og[rowbase + (size_t)(q0 + q) * 768 + d0]) = v;
  }
}

// ---------------------------------------------------------------------------
// Temporal attention (causal over S=16), LDS-staged (unchanged).
// ---------------------------------------------------------------------------
__global__ __launch_bounds__(192)
void temporal_attn_kernel(const short* __restrict__ Qg, const short* __restrict__ Kg,
                          const short* __restrict__ Vg, short* __restrict__ Og)
{
  const int bp = blockIdx.x;
  const int b = bp >> 8, p = bp & 255;

  __shared__ short Ks[16 * 768];
  __shared__ short Vs[16 * 768];

  const int tid = threadIdx.x;
  const size_t gbase = ((size_t)(b * 16) * 256 + p) * 768;
  constexpr int SROW = 256 * 768;

  {
    const int half = tid / 96;
    const int cc   = tid - half * 96;
    const int c    = cc & 7, hs = cc >> 3;
    const int ldso = (c * 12 + hs) * 8;
#pragma unroll
    for (int it = 0; it < 8; ++it) {
      const int s = it * 2 + half;
      const size_t ga = gbase + (size_t)s * SROW + cc * 8;
      *reinterpret_cast<s16x8*>(&Ks[s * 768 + ldso]) =
          *reinterpret_cast<const s16x8*>(&Kg[ga]);
      *reinterpret_cast<s16x8*>(&Vs[s * 768 + ldso]) =
          *reinterpret_cast<const s16x8*>(&Vg[ga]);
    }
  }
  __syncthreads();

  const int h = tid % 12, i = tid / 12;
  const float scale = 0.125f;
  const size_t qoff = gbase + (size_t)i * SROW + h * 64;

  float q[HDc];
#pragma unroll
  for (int c = 0; c < 8; ++c) {
    s16x8 v = *reinterpret_cast<const s16x8*>(&Qg[qoff + c * 8]);
#pragma unroll
    for (int e = 0; e < 8; ++e) q[c * 8 + e] = bf2f(v[e]) * scale;
  }

  float m = -INFINITY, l = 0.f;
  float o[HDc];
#pragma unroll
  for (int d = 0; d < HDc; ++d) o[d] = 0.f;

  for (int j = 0; j <= i; ++j) {
    const short* kr = &Ks[j * 768];
    float s = 0.f;
#pragma unroll
    for (int c = 0; c < 8; ++c) {
      s16x8 kv = *reinterpret_cast<const s16x8*>(kr + (c * 12 + h) * 8);
#pragma unroll
      for (int e = 0; e < 8; ++e) s += q[c * 8 + e] * bf2f(kv[e]);
    }
    float mn   = fmaxf(m, s);
    float corr = __expf(m - mn);
    float pw   = __expf(s - mn);
    l = l * corr + pw;
    const short* vr = &Vs[j * 768];
#pragma unroll
    for (int c = 0; c < 8; ++c) {
      s16x8 vv = *reinterpret_cast<const s16x8*>(vr + (c * 12 + h) * 8);
#pragma unroll
      for (int e = 0; e < 8; ++e)
        o[c * 8 + e] = fmaf(pw, bf2f(vv[e]), o[c * 8 + e] * corr);
    }
    m = mn;
  }
  const float inv = 1.f / l;
  short* op = &Og[qoff];
#pragma unroll
  for (int c = 0; c < 8; ++c) {
    s16x8 v;
#pragma unroll
    for (int e = 0; e < 8; ++e) v[e] = f2bf(o[c * 8 + e] * inv);
    *reinterpret_cast<s16x8*>(op + c * 8) = v;
  }
}

// ---------------------------------------------------------------------------
// LayerNorm over E=768 (bf16 input U): one wave per row, 4 rows per block.
// ---------------------------------------------------------------------------
template<bool OUTBF>
__global__ __launch_bounds__(256)
void layernorm_kernel(const short* __restrict__ U, const float* __restrict__ g,
                      const float* __restrict__ be, void* __restrict__ outv)
{
  const int tid  = threadIdx.x;
  const int lane = tid & 63, w = tid >> 6;
  const size_t row = (size_t)blockIdx.x * 4 + w;
  const short* u = U + row * Ec;

  float x[12];
#pragma unroll
  for (int c = 0; c < 3; ++c) {
    s16x4 v = *reinterpret_cast<const s16x4*>(&u[c * 256 + lane * 4]);
    x[c*4+0] = bf2f(v[0]); x[c*4+1] = bf2f(v[1]);
    x[c*4+2] = bf2f(v[2]); x[c*4+3] = bf2f(v[3]);
  }
  float s = 0.f;
#pragma unroll
  for (int k = 0; k < 12; ++k) s += x[k];
#pragma unroll
  for (int off = 32; off > 0; off >>= 1) s += __shfl_xor(s, off, 64);
  const float mean = s * (1.f / 768.f);

  float vs = 0.f;
#pragma unroll
  for (int k = 0; k < 12; ++k) { float d = x[k] - mean; vs += d * d; }
#pragma unroll
  for (int off = 32; off > 0; off >>= 1) vs += __shfl_xor(vs, off, 64);
  const float rs = rsqrtf(vs * (1.f / 768.f) + 1e-5f);

#pragma unroll
  for (int c = 0; c < 3; ++c) {
    int idx = c * 256 + lane * 4;
    float4 gv = *reinterpret_cast<const float4*>(&g[idx]);
    float4 bv = *reinterpret_cast<const float4*>(&be[idx]);
    float r0 = (x[c*4+0] - mean) * rs * gv.x + bv.x;
    float r1 = (x[c*4+1] - mean) * rs * gv.y + bv.y;
    float r2 = (x[c*4+2] - mean) * rs * gv.z + bv.z;
    float r3 = (x[c*4+3] - mean) * rs * gv.w + bv.w;
    if (OUTBF) {
      short* op = (short*)outv + row * Ec + idx;
      s16x4 v = { f2bf(r0), f2bf(r1), f2bf(r2), f2bf(r3) };
      *reinterpret_cast<s16x4*>(op) = v;
    } else {
      float* op = (float*)outv + row * Ec + idx;
      *reinterpret_cast<float4*>(op) = make_float4(r0, r1, r2, r3);
    }
  }
}

// ---------------------------------------------------------------------------
extern "C" void kernel_launch(void* const* d_in, const int* in_sizes, int n_in,
                              void* d_out, int out_size, void* d_ws, size_t ws_size,
                              hipStream_t stream)
{
  const float* x       = (const float*)d_in[0];
  const float* sa_wqkv = (const float*)d_in[1];
  const float* sa_bqkv = (const float*)d_in[2];
  const float* sa_wo   = (const float*)d_in[3];
  const float* sa_bo   = (const float*)d_in[4];
  const float* sa_g    = (const float*)d_in[5];
  const float* sa_b    = (const float*)d_in[6];
  const float* ta_wqkv = (const float*)d_in[7];
  const float* ta_bqkv = (const float*)d_in[8];
  const float* ta_wo   = (const float*)d_in[9];
  const float* ta_bo   = (const float*)d_in[10];
  const float* ta_g    = (const float*)d_in[11];
  const float* ta_b    = (const float*)d_in[12];
  const float* f_w1    = (const float*)d_in[13];
  const float* f_b1    = (const float*)d_in[14];
  const float* f_w2    = (const float*)d_in[15];
  const float* f_b2    = (const float*)d_in[16];
  const float* f_g     = (const float*)d_in[17];
  const float* f_b     = (const float*)d_in[18];

  float* out = (float*)d_out;

  constexpr size_t EE = (size_t)Ec * Ec;
  constexpr size_t WTOT = 3*EE + EE + 3*EE + EE + 2*(size_t)Ec*FFc;  // 9,437,184
  const size_t need = 12 * ME + 2 * WTOT;
  if (ws_size < need) return;

  short* Xb  = (short*)d_ws;
  short* Qb  = Xb + ME;
  short* Kb  = Qb + ME;
  short* Vtb = Qb + 2 * ME;
  short* Hb  = Qb;              // FFN hidden reuses [1ME,5ME)
  short* U   = Xb + 5 * ME;
  short* Wtb = U + ME;

  short* wt_sa_qkv = Wtb;
  short* wt_sa_wo  = wt_sa_qkv + 3 * EE;
  short* wt_ta_qkv = wt_sa_wo  + EE;
  short* wt_ta_wo  = wt_ta_qkv + 3 * EE;
  short* wt_f_w1   = wt_ta_wo  + EE;
  short* wt_f_w2   = wt_f_w1   + (size_t)Ec * FFc;

  prep_kernel<<<8448, 256, 0, stream>>>(
      x, Xb, sa_wqkv, wt_sa_qkv, sa_wo, wt_sa_wo,
      ta_wqkv, wt_ta_qkv, ta_wo, wt_ta_wo, f_w1, wt_f_w1, f_w2, wt_f_w2);

  // grids: gemm192 -> (M/256)*(N/192); gemm256 -> (M/256)*(N/256)
  const dim3 gQKV((Mrows / 256) * (Ec / 192), 1, 3);      // 256 x3 = 3 rounds
  const dim3 gSQ ((Mrows / 256) * (Ec / 192), 1, 1);      // 256 = 1 round
  const dim3 gFF1((Mrows / 256) * (FFc / 256), 1, 1);     // 768 = 3 rounds

  // ---- Stage A: spatial attention ----
  gemm192_kernel<4><<<gQKV, 512, 0, stream>>>(Xb, wt_sa_qkv, sa_bqkv, nullptr, Qb, Vtb, Mrows, Ec, Ec);
  spatial_attn_kernel<<<dim3(Bc * Sc, Hc, 2), 256, 0, stream>>>(Qb, Kb, Vtb, Qb);
  gemm192_kernel<3><<<gSQ, 512, 0, stream>>>(Qb, wt_sa_wo, sa_bo, Xb, U, nullptr, Mrows, Ec, Ec);
  layernorm_kernel<true><<<Mrows / 4, 256, 0, stream>>>(U, sa_g, sa_b, Xb);

  // ---- Stage B: temporal attention ----
  gemm192_kernel<0><<<gQKV, 512, 0, stream>>>(Xb, wt_ta_qkv, ta_bqkv, nullptr, Qb, nullptr, Mrows, Ec, Ec);
  temporal_attn_kernel<<<Bc * Pc, 192, 0, stream>>>(Qb, Kb, Vtb, Qb);
  gemm192_kernel<3><<<gSQ, 512, 0, stream>>>(Qb, wt_ta_wo, ta_bo, Xb, U, nullptr, Mrows, Ec, Ec);
  layernorm_kernel<true><<<Mrows / 4, 256, 0, stream>>>(U, ta_g, ta_b, Xb);

  // ---- Stage C: FFN ----
  gemm256_kernel<1><<<gFF1, 512, 0, stream>>>(Xb, wt_f_w1, f_b1, nullptr, Hb, nullptr, Mrows, FFc, Ec);
  gemm192_kernel<3><<<gSQ, 512, 0, stream>>>(Hb, wt_f_w2, f_b2, Xb, U, nullptr, Mrows, Ec, FFc);
  layernorm_kernel<false><<<Mrows / 4, 256, 0, stream>>>(U, f_g, f_b, out);
}

// Round 14
// 516.639 us; speedup vs baseline: 1.1391x; 1.1391x over previous
//
#include <hip/hip_runtime.h>
#include <hip/hip_bf16.h>
#include <math.h>

// Problem constants
constexpr int Bc = 4, Sc = 16, Pc = 256, Ec = 768, Hc = 12, HDc = 64, FFc = 3072;
constexpr int Mrows = Bc * Sc * Pc;              // 16384 token rows
constexpr size_t ME = (size_t)Mrows * Ec;        // 12,582,912 elements

typedef __attribute__((ext_vector_type(4))) float f32x4;
typedef __attribute__((ext_vector_type(8))) short s16x8;
typedef __attribute__((ext_vector_type(4))) short s16x4;

__device__ __forceinline__ short f2bf(float f) {
  union { float f; unsigned u; } v; v.f = f;
  unsigned r = (v.u + 0x7FFFu + ((v.u >> 16) & 1u)) >> 16;  // RNE
  return (short)r;
}
__device__ __forceinline__ float bf2f(short s) {
  union { unsigned u; float f; } v; v.u = ((unsigned)(unsigned short)s) << 16;
  return v.f;
}

// async global->LDS, 16B per lane; lds dest is wave-uniform base + lane*16.
// Source must be lane-contiguous (R9 lesson).
__device__ __forceinline__ void async16(const void* g, void* l) {
  __builtin_amdgcn_global_load_lds(
      (const __attribute__((address_space(1))) unsigned int*)g,
      (__attribute__((address_space(3))) unsigned int*)l, 16, 0, 0);
}

// ---------------------------------------------------------------------------
// Unified prep kernel: 6 weight transpose-converts + x->bf16, one dispatch.
// ---------------------------------------------------------------------------
__device__ __forceinline__ void wtrans_tile(const float* __restrict__ W,
                                            short* __restrict__ Wt,
                                            int K, int N, int n0, int k0, int t)
{
  const int n  = n0 + (t >> 2);
  const int kc = k0 + (t & 3) * 16;
  short buf[16];
#pragma unroll
  for (int i = 0; i < 16; ++i)
    buf[i] = f2bf(W[(size_t)(kc + i) * N + n]);
  *reinterpret_cast<s16x8*>(&Wt[(size_t)n * K + kc])     = *reinterpret_cast<s16x8*>(&buf[0]);
  *reinterpret_cast<s16x8*>(&Wt[(size_t)n * K + kc + 8]) = *reinterpret_cast<s16x8*>(&buf[8]);
}

__global__ __launch_bounds__(256)
void prep_kernel(const float* __restrict__ x, short* __restrict__ Xb,
                 const float* __restrict__ saqkv, short* __restrict__ wt_saqkv,
                 const float* __restrict__ sawo,  short* __restrict__ wt_sawo,
                 const float* __restrict__ taqkv, short* __restrict__ wt_taqkv,
                 const float* __restrict__ tawo,  short* __restrict__ wt_tawo,
                 const float* __restrict__ fw1,   short* __restrict__ wt_fw1,
                 const float* __restrict__ fw2,   short* __restrict__ wt_fw2)
{
  const int b = blockIdx.x;
  const int t = threadIdx.x;
  constexpr size_t EE = (size_t)Ec * Ec;

  if (b < 432) {
    const int z = b / 144, tl = b % 144;
    wtrans_tile(saqkv + (size_t)z * EE, wt_saqkv + (size_t)z * EE,
                Ec, Ec, (tl % 12) * 64, (tl / 12) * 64, t);
  } else if (b < 576) {
    const int tl = b - 432;
    wtrans_tile(sawo, wt_sawo, Ec, Ec, (tl % 12) * 64, (tl / 12) * 64, t);
  } else if (b < 1008) {
    const int z = (b - 576) / 144, tl = (b - 576) % 144;
    wtrans_tile(taqkv + (size_t)z * EE, wt_taqkv + (size_t)z * EE,
                Ec, Ec, (tl % 12) * 64, (tl / 12) * 64, t);
  } else if (b < 1152) {
    const int tl = b - 1008;
    wtrans_tile(tawo, wt_tawo, Ec, Ec, (tl % 12) * 64, (tl / 12) * 64, t);
  } else if (b < 1728) {
    const int tl = b - 1152;
    wtrans_tile(fw1, wt_fw1, Ec, FFc, (tl % 48) * 64, (tl / 48) * 64, t);
  } else if (b < 2304) {
    const int tl = b - 1728;
    wtrans_tile(fw2, wt_fw2, FFc, Ec, (tl % 12) * 64, (tl / 12) * 64, t);
  } else {
    const size_t i = (size_t)(b - 2304) * 256 + t;
    const float4* p = reinterpret_cast<const float4*>(x + i * 8);
    float4 a = p[0], bb = p[1];
    s16x8 o = { f2bf(a.x), f2bf(a.y), f2bf(a.z), f2bf(a.w),
                f2bf(bb.x), f2bf(bb.y), f2bf(bb.z), f2bf(bb.w) };
    *reinterpret_cast<s16x8*>(Xb + i * 8) = o;
  }
}

// ---------------------------------------------------------------------------
// Shared GEMM phase machinery (R12 structure — measured best at 522 us).
// Begin-barrier removed (R11); per-phase fragment reads keep the live set
// <= ~120 VGPR (R13 lesson: whole-tile reads spill at this occupancy).
// ---------------------------------------------------------------------------
#define LDFRAG(base, row, kc) \
  (*reinterpret_cast<const s16x8*>((base) + (row) * 128 + ((((kc) ^ ((row) & 7)) << 4))))

#define PH_MMA_BEGIN \
  do { \
    asm volatile("s_waitcnt lgkmcnt(0)" ::: "memory"); \
    __builtin_amdgcn_sched_barrier(0); \
    __builtin_amdgcn_s_setprio(1); \
  } while (0)

#define PH_END \
  do { __builtin_amdgcn_s_setprio(0); __builtin_amdgcn_s_barrier(); \
       __builtin_amdgcn_sched_barrier(0); } while (0)

// Conditional counted-vmcnt tile end (tail drains fully).
#define PH_END_VMC(cond, nstr) \
  do { \
    __builtin_amdgcn_s_setprio(0); \
    if (cond) asm volatile("s_waitcnt vmcnt(" nstr ")" ::: "memory"); \
    else      asm volatile("s_waitcnt vmcnt(0)" ::: "memory"); \
    __builtin_amdgcn_sched_barrier(0); \
    __builtin_amdgcn_s_barrier(); \
    __builtin_amdgcn_sched_barrier(0); \
  } while (0)

// ---------------------------------------------------------------------------
// GEMM 256x256 (BN=256), 8 phases / 2 K-tiles, BK=64 — used for FF1.
// OUT: 1 = bf16 + relu.
// ---------------------------------------------------------------------------
#define PH_READS(Aslot, Bslot, q, LDB) \
  do { \
    if (LDB) { \
      _Pragma("unroll") \
      for (int nj = 0; nj < 4; ++nj) { \
        bfr[nj][0] = LDFRAG((Bslot), wc * 64 + nj * 16 + l16, g); \
        bfr[nj][1] = LDFRAG((Bslot), wc * 64 + nj * 16 + l16, 4 + g); \
      } \
    } \
    _Pragma("unroll") \
    for (int mi = 0; mi < 2; ++mi) { \
      const int arow = wr * 128 + ((q) * 2 + mi) * 16 + l16; \
      afr[mi][0] = LDFRAG((Aslot), arow, g); \
      afr[mi][1] = LDFRAG((Aslot), arow, 4 + g); \
    } \
  } while (0)

#define PH_MMA4(q) \
  do { \
    PH_MMA_BEGIN; \
    _Pragma("unroll") \
    for (int mi = 0; mi < 2; ++mi) \
      _Pragma("unroll") \
      for (int nj = 0; nj < 4; ++nj) { \
        acc[(q) * 2 + mi][nj] = __builtin_amdgcn_mfma_f32_16x16x32_bf16( \
            afr[mi][0], bfr[nj][0], acc[(q) * 2 + mi][nj], 0, 0, 0); \
        acc[(q) * 2 + mi][nj] = __builtin_amdgcn_mfma_f32_16x16x32_bf16( \
            afr[mi][1], bfr[nj][1], acc[(q) * 2 + mi][nj], 0, 0, 0); \
      } \
  } while (0)

template<int OUT>
__global__ __launch_bounds__(512, 2)
void gemm256_kernel(const short* __restrict__ A, const short* __restrict__ Wt,
                    const float* __restrict__ biasg, const void* __restrict__ resv,
                    void* __restrict__ Cg, short* __restrict__ vt,
                    int M, int N, int K)
{
  __shared__ char smem[131072];
  const int z = blockIdx.z;
  const short* __restrict__ Wz = Wt + (size_t)z * (size_t)N * K;
  const float* __restrict__ bz = biasg + (size_t)z * N;

  const int nwg = gridDim.x;
  const int swz = ((int)blockIdx.x & 7) * (nwg >> 3) + ((int)blockIdx.x >> 3);
  const int NT = N >> 8;
  const int bm = (swz / NT) << 8;
  const int bn = (swz % NT) << 8;

  const int tid  = threadIdx.x;
  const int lane = tid & 63;
  const int wid  = tid >> 6;
  const int wr   = wid >> 2;
  const int wc   = wid & 3;
  const int l16  = lane & 15;
  const int g    = lane >> 4;

  char* const As0 = smem;
  char* const Bs0 = smem + 32768;
  char* const As1 = smem + 65536;
  char* const Bs1 = smem + 98304;

  const int srow = lane >> 3;
  const int scol = ((lane & 7) ^ srow) * 8;
  const int ldso = wid * 1024;

  auto stageG = [&](const short* __restrict__ G, int grow0, int k0, char* ldsHalf) {
    const size_t r0 = (size_t)(grow0 + wid * 8 + srow);
    async16(G + r0 * K + (k0 + scol), ldsHalf + ldso);
    async16(G + (r0 + 64) * K + (k0 + scol), ldsHalf + 8192 + ldso);
  };

  f32x4 acc[8][4];
  s16x8 bfr[4][2];
  s16x8 afr[2][2];
#pragma unroll
  for (int mi = 0; mi < 8; ++mi)
#pragma unroll
    for (int nj = 0; nj < 4; ++nj) acc[mi][nj] = f32x4{0.f, 0.f, 0.f, 0.f};

  const int ntile = K >> 6;
  const int nit   = ntile >> 1;

  stageG(A,  bm,        0,  As0);
  stageG(A,  bm + 128,  0,  As0 + 16384);
  stageG(Wz, bn,        0,  Bs0);
  stageG(Wz, bn + 128,  0,  Bs0 + 16384);
  stageG(Wz, bn,        64, Bs1);
  stageG(Wz, bn + 128,  64, Bs1 + 16384);
  asm volatile("s_waitcnt vmcnt(4)" ::: "memory");
  __builtin_amdgcn_sched_barrier(0);
  __builtin_amdgcn_s_barrier();

  for (int j = 0; j < nit; ++j) {
    const int t1k = (2 * j + 1) << 6;
    const int t2k = (2 * j + 2) << 6;
    const int t3k = (2 * j + 3) << 6;
    const bool s2 = (2 * j + 2) < ntile;
    const bool s3 = (2 * j + 3) < ntile;

    PH_READS(As0, Bs0, 0, true);
    stageG(A, bm, t1k, As1);
    PH_MMA4(0); PH_END;

    PH_READS(As0, Bs0, 1, false);
    stageG(A, bm + 128, t1k, As1 + 16384);
    PH_MMA4(1); PH_END;

    PH_READS(As0, Bs0, 2, false);
    if (s2) stageG(Wz, bn, t2k, Bs0);
    PH_MMA4(2); PH_END;

    PH_READS(As0, Bs0, 3, false);
    if (s2) stageG(Wz, bn + 128, t2k, Bs0 + 16384);
    PH_MMA4(3); PH_END_VMC(s2, "4");

    PH_READS(As1, Bs1, 0, true);
    if (s2) stageG(A, bm, t2k, As0);
    PH_MMA4(0); PH_END;

    PH_READS(As1, Bs1, 1, false);
    if (s2) stageG(A, bm + 128, t2k, As0 + 16384);
    PH_MMA4(1); PH_END;

    PH_READS(As1, Bs1, 2, false);
    if (s3) stageG(Wz, bn, t3k, Bs1);
    PH_MMA4(2); PH_END;

    PH_READS(As1, Bs1, 3, false);
    if (s3) stageG(Wz, bn + 128, t3k, Bs1 + 16384);
    PH_MMA4(3); PH_END_VMC(s3, "4");
  }

  short* Cb = (short*)Cg + (size_t)z * (size_t)M * N;
#pragma unroll
  for (int mi = 0; mi < 8; ++mi) {
    const int row0 = bm + wr * 128 + mi * 16 + g * 4;
#pragma unroll
    for (int nj = 0; nj < 4; ++nj) {
      const int col = bn + wc * 64 + nj * 16 + l16;
      const float bias = bz[col];
#pragma unroll
      for (int r = 0; r < 4; ++r) {
        float v = acc[mi][nj][r] + bias;
        size_t idx = (size_t)(row0 + r) * N + col;
        if (OUT == 1) v = fmaxf(v, 0.f);
        Cb[idx] = f2bf(v);
      }
    }
  }
}

// ---------------------------------------------------------------------------
// GEMM 256x192 (BN=192), 3 phases per K-tile, BK=64 — N=768 family.
// vmcnt ring: 7 loads/tile (A:4, B:3) -> vmcnt(3) at each tile end.
// OUT: 0 bf16 | 3 bf16 + bf16 residual | 4 QKV-A (z==2 -> transposed-V)
// ---------------------------------------------------------------------------
#define R_READ_A(Aslot, m0, mcnt) \
  do { \
    _Pragma("unroll") \
    for (int mi = (m0); mi < (m0) + (mcnt); ++mi) { \
      const int arow = wr * 128 + mi * 16 + l16; \
      afr[mi][0] = LDFRAG((Aslot), arow, g); \
      afr[mi][1] = LDFRAG((Aslot), arow, 4 + g); \
    } \
  } while (0)

#define R_READ_B(Bslot) \
  do { \
    _Pragma("unroll") \
    for (int nj = 0; nj < 3; ++nj) { \
      const int brow = wc * 48 + nj * 16 + l16; \
      bfr[nj][0] = LDFRAG((Bslot), brow, g); \
      bfr[nj][1] = LDFRAG((Bslot), brow, 4 + g); \
    } \
  } while (0)

#define R_MMA(p) \
  do { \
    PH_MMA_BEGIN; \
    _Pragma("unroll") \
    for (int pi = 8 * (p); pi < 8 * (p) + 8; ++pi) { \
      const int mi = pi / 3, nj = pi % 3; \
      acc[mi][nj] = __builtin_amdgcn_mfma_f32_16x16x32_bf16( \
          afr[mi][0], bfr[nj][0], acc[mi][nj], 0, 0, 0); \
      acc[mi][nj] = __builtin_amdgcn_mfma_f32_16x16x32_bf16( \
          afr[mi][1], bfr[nj][1], acc[mi][nj], 0, 0, 0); \
    } \
  } while (0)

template<int OUT>
__global__ __launch_bounds__(512, 2)
void gemm192_kernel(const short* __restrict__ A, const short* __restrict__ Wt,
                    const float* __restrict__ biasg, const void* __restrict__ resv,
                    void* __restrict__ Cg, short* __restrict__ vt,
                    int M, int N, int K)
{
  __shared__ char smem[114688];   // As0 32K | As1 32K | Bs0 24K | Bs1 24K
  const int z = blockIdx.z;
  const short* __restrict__ Wz = Wt + (size_t)z * (size_t)N * K;
  const float* __restrict__ bz = biasg + (size_t)z * N;

  const int nwg = gridDim.x;
  const int swz = ((int)blockIdx.x & 7) * (nwg >> 3) + ((int)blockIdx.x >> 3);
  const int NT = N / 192;
  const int bm = (swz / NT) << 8;
  const int bn = (swz % NT) * 192;

  const int tid  = threadIdx.x;
  const int lane = tid & 63;
  const int wid  = tid >> 6;
  const int wr   = wid >> 2;
  const int wc   = wid & 3;
  const int l16  = lane & 15;
  const int g    = lane >> 4;

  char* const As0 = smem;
  char* const As1 = smem + 32768;
  char* const Bs0 = smem + 65536;
  char* const Bs1 = smem + 90112;

  const int srow = lane >> 3;
  const int scol = ((lane & 7) ^ srow) * 8;
  const int ldso = wid * 1024;

  auto stageG = [&](const short* __restrict__ G, int grow0, int k0, char* ldsHalf) {
    const size_t r0 = (size_t)(grow0 + wid * 8 + srow);
    async16(G + r0 * K + (k0 + scol), ldsHalf + ldso);
    async16(G + (r0 + 64) * K + (k0 + scol), ldsHalf + 8192 + ldso);
  };
  auto stageB = [&](const short* __restrict__ G, int grow0, int k0, char* ldsB) {
    const size_t r0 = (size_t)(grow0 + wid * 8 + srow);
    async16(G + r0 * K + (k0 + scol), ldsB + ldso);
    async16(G + (r0 + 64) * K + (k0 + scol), ldsB + 8192 + ldso);
    async16(G + (r0 + 128) * K + (k0 + scol), ldsB + 16384 + ldso);
  };

  f32x4 acc[8][3];
  s16x8 afr[8][2];
  s16x8 bfr[3][2];
#pragma unroll
  for (int mi = 0; mi < 8; ++mi)
#pragma unroll
    for (int nj = 0; nj < 3; ++nj) acc[mi][nj] = f32x4{0.f, 0.f, 0.f, 0.f};

  const int ntile = K >> 6;
  const int nit   = ntile >> 1;

  stageG(A,  bm,       0,  As0);
  stageG(A,  bm + 128, 0,  As0 + 16384);
  stageB(Wz, bn,       0,  Bs0);
  stageB(Wz, bn,       64, Bs1);
  asm volatile("s_waitcnt vmcnt(3)" ::: "memory");
  __builtin_amdgcn_sched_barrier(0);
  __builtin_amdgcn_s_barrier();

  for (int j = 0; j < nit; ++j) {
    const int t1k = (2 * j + 1) << 6;
    const int t2k = (2 * j + 2) << 6;
    const int t3k = (2 * j + 3) << 6;
    const bool s2 = (2 * j + 2) < ntile;
    const bool s3 = (2 * j + 3) < ntile;

    // ---- tile 2j (As0/Bs0), 3 phases ----
    R_READ_A(As0, 0, 3); R_READ_B(Bs0);
    stageG(A, bm, t1k, As1);
    R_MMA(0); PH_END;

    R_READ_A(As0, 3, 3);
    stageG(A, bm + 128, t1k, As1 + 16384);
    R_MMA(1); PH_END;

    R_READ_A(As0, 6, 2);
    if (s2) stageB(Wz, bn, t2k, Bs0);        // Bs0 reads done at ph0
    R_MMA(2); PH_END_VMC(s2, "3");           // forces A(t1),B(t1) landed

    // ---- tile 2j+1 (As1/Bs1), 3 phases ----
    R_READ_A(As1, 0, 3); R_READ_B(Bs1);
    if (s2) { stageG(A, bm, t2k, As0); }     // As0 reads done last tile
    R_MMA(0); PH_END;

    R_READ_A(As1, 3, 3);
    if (s2) stageG(A, bm + 128, t2k, As0 + 16384);
    R_MMA(1); PH_END;

    R_READ_A(As1, 6, 2);
    if (s3) stageB(Wz, bn, t3k, Bs1);        // Bs1 reads done at ph3
    R_MMA(2); PH_END_VMC(s3, "3");           // forces A(t2),B(t2) landed
  }

  const short* resb = (const short*)resv;
  short* Cb = (short*)Cg + (size_t)z * (size_t)M * N;

#pragma unroll
  for (int mi = 0; mi < 8; ++mi) {
    const int row0 = bm + wr * 128 + mi * 16 + g * 4;
#pragma unroll
    for (int nj = 0; nj < 3; ++nj) {
      const int col = bn + wc * 48 + nj * 16 + l16;
      if (OUT == 4 && z == 2) {
        const int bs2 = row0 >> 8, p0 = row0 & 255;
        const int h2 = col >> 6,  d2 = col & 63;
        const float bias = bz[col];
        s16x4 v = { f2bf(acc[mi][nj][0] + bias), f2bf(acc[mi][nj][1] + bias),
                    f2bf(acc[mi][nj][2] + bias), f2bf(acc[mi][nj][3] + bias) };
        *reinterpret_cast<s16x4*>(
            &vt[(((size_t)bs2 * 12 + h2) * 64 + d2) * 256 + p0]) = v;
      } else {
        const float bias = bz[col];
#pragma unroll
        for (int r = 0; r < 4; ++r) {
          float v = acc[mi][nj][r] + bias;
          size_t idx = (size_t)(row0 + r) * N + col;
          if (OUT == 3) v += bf2f(resb[idx]);
          Cb[idx] = f2bf(v);
        }
      }
    }
  }
}

// ---------------------------------------------------------------------------
// Spatial attention, MFMA flash, barrier-free (unchanged).
// ---------------------------------------------------------------------------
__global__ __launch_bounds__(256, 3)
void spatial_attn_kernel(const short* __restrict__ Qg, const short* __restrict__ Kg,
                         const short* __restrict__ Vt, short* __restrict__ Og)
{
  const int bs = blockIdx.x;
  const int h  = blockIdx.y;

  __shared__ short Pl[4 * 32 * 64];

  const int tid  = threadIdx.x;
  const int lane = tid & 63;
  const int wid  = tid >> 6;
  const int l16  = lane & 15;
  const int g    = lane >> 4;
  const int q0   = blockIdx.z * 128 + wid * 32;
  char* Pw = (char*)Pl + wid * 4096;

  const size_t rowbase = (size_t)(bs * 256) * 768 + h * 64;
  const size_t vbase   = ((size_t)bs * 12 + h) * 64 * 256;

  s16x8 qa[2][2];
#pragma unroll
  for (int m = 0; m < 2; ++m)
#pragma unroll
    for (int ks = 0; ks < 2; ++ks)
      qa[m][ks] = *reinterpret_cast<const s16x8*>(
          &Qg[rowbase + (size_t)(q0 + m * 16 + l16) * 768 + ks * 32 + g * 8]);

  float mrun[2][4], lrun[2][4];
  f32x4 oac[2][4];
#pragma unroll
  for (int m = 0; m < 2; ++m)
#pragma unroll
    for (int r = 0; r < 4; ++r) { mrun[m][r] = -INFINITY; lrun[m][r] = 0.f; }
#pragma unroll
  for (int m = 0; m < 2; ++m)
#pragma unroll
    for (int n = 0; n < 4; ++n) oac[m][n] = f32x4{0.f, 0.f, 0.f, 0.f};

#pragma unroll
  for (int t = 0; t < 4; ++t) {
    const int key0 = t * 64;
    f32x4 sc[2][4];
#pragma unroll
    for (int m = 0; m < 2; ++m)
#pragma unroll
      for (int n = 0; n < 4; ++n) sc[m][n] = f32x4{0.f, 0.f, 0.f, 0.f};
#pragma unroll
    for (int ks = 0; ks < 2; ++ks) {
      s16x8 kf[4];
#pragma unroll
      for (int n = 0; n < 4; ++n) {
        const int key = key0 + n * 16 + l16;
        kf[n] = *reinterpret_cast<const s16x8*>(
            &Kg[rowbase + (size_t)key * 768 + ks * 32 + g * 8]);
      }
#pragma unroll
      for (int m = 0; m < 2; ++m)
#pragma unroll
        for (int n = 0; n < 4; ++n)
          sc[m][n] = __builtin_amdgcn_mfma_f32_16x16x32_bf16(qa[m][ks], kf[n], sc[m][n], 0, 0, 0);
    }
#pragma unroll
    for (int m = 0; m < 2; ++m)
#pragma unroll
      for (int n = 0; n < 4; ++n)
#pragma unroll
        for (int r = 0; r < 4; ++r) sc[m][n][r] *= 0.125f;

#pragma unroll
    for (int m = 0; m < 2; ++m) {
#pragma unroll
      for (int r = 0; r < 4; ++r) {
        float mx = fmaxf(fmaxf(sc[m][0][r], sc[m][1][r]), fmaxf(sc[m][2][r], sc[m][3][r]));
#pragma unroll
        for (int mk = 1; mk < 16; mk <<= 1) mx = fmaxf(mx, __shfl_xor(mx, mk, 64));
        const float mnew = fmaxf(mrun[m][r], mx);
        const float corr = __expf(mrun[m][r] - mnew);
        mrun[m][r] = mnew;
        float rs = 0.f;
#pragma unroll
        for (int n = 0; n < 4; ++n) {
          float p = __expf(sc[m][n][r] - mnew);
          sc[m][n][r] = p;
          rs += p;
        }
#pragma unroll
        for (int mk = 1; mk < 16; mk <<= 1) rs += __shfl_xor(rs, mk, 64);
        lrun[m][r] = lrun[m][r] * corr + rs;
#pragma unroll
        for (int nd = 0; nd < 4; ++nd) oac[m][nd][r] *= corr;
      }
    }
#pragma unroll
    for (int m = 0; m < 2; ++m)
#pragma unroll
      for (int n = 0; n < 4; ++n)
#pragma unroll
        for (int r = 0; r < 4; ++r) {
          const int q = m * 16 + g * 4 + r;
          const int key = n * 16 + l16;
          const int byte = q * 128 + (((key >> 3) ^ (q & 7)) * 16) + (key & 7) * 2;
          *reinterpret_cast<short*>(Pw + byte) = f2bf(sc[m][n][r]);
        }
#pragma unroll
    for (int ks = 0; ks < 2; ++ks) {
      s16x8 pa[2], vf[4];
#pragma unroll
      for (int m = 0; m < 2; ++m) {
        const int q = m * 16 + l16;
        const int s = ks * 4 + g;
        pa[m] = *reinterpret_cast<const s16x8*>(Pw + q * 128 + ((s ^ (q & 7)) * 16));
      }
#pragma unroll
      for (int nd = 0; nd < 4; ++nd) {
        const int d = nd * 16 + l16;
        const int key = key0 + ks * 32 + g * 8;
        vf[nd] = *reinterpret_cast<const s16x8*>(&Vt[vbase + (size_t)d * 256 + key]);
      }
#pragma unroll
      for (int m = 0; m < 2; ++m)
#pragma unroll
        for (int nd = 0; nd < 4; ++nd)
          oac[m][nd] = __builtin_amdgcn_mfma_f32_16x16x32_bf16(pa[m], vf[nd], oac[m][nd], 0, 0, 0);
    }
  }

#pragma unroll
  for (int m = 0; m < 2; ++m)
#pragma unroll
    for (int r = 0; r < 4; ++r) {
      const float inv = 1.f / lrun[m][r];
#pragma unroll
      for (int nd = 0; nd < 4; ++nd) oac[m][nd][r] *= inv;
    }
#pragma unroll
  for (int m = 0; m < 2; ++m)
#pragma unroll
    for (int nd = 0; nd < 4; ++nd)
#pragma unroll
      for (int r = 0; r < 4; ++r) {
        const int q = m * 16 + g * 4 + r;
        const int d = nd * 16 + l16;
        const int byte = q * 128 + (((d >> 3) ^ (q & 7)) * 16) + (d & 7) * 2;
        *reinterpret_cast<short*>(Pw + byte) = f2bf(oac[m][nd][r]);
      }
#pragma unroll
  for (int it = 0; it < 4; ++it) {
    const int slot = it * 64 + lane;
    const int q = slot >> 3, sl = slot & 7;
    const int d0 = (sl ^ (q & 7)) * 8;
    s16x8 v = *reinterpret_cast<const s16x8*>(Pw + slot * 16);
    *reinterpret_cast<s16x8*>(
        &Og[rowbase + (size_t)(q0 + q) * 768 + d0]) = v;
  }
}

// ---------------------------------------------------------------------------
// Temporal attention (causal over S=16), LDS-staged (unchanged).
// ---------------------------------------------------------------------------
__global__ __launch_bounds__(192)
void temporal_attn_kernel(const short* __restrict__ Qg, const short* __restrict__ Kg,
                          const short* __restrict__ Vg, short* __restrict__ Og)
{
  const int bp = blockIdx.x;
  const int b = bp >> 8, p = bp & 255;

  __shared__ short Ks[16 * 768];
  __shared__ short Vs[16 * 768];

  const int tid = threadIdx.x;
  const size_t gbase = ((size_t)(b * 16) * 256 + p) * 768;
  constexpr int SROW = 256 * 768;

  {
    const int half = tid / 96;
    const int cc   = tid - half * 96;
    const int c    = cc & 7, hs = cc >> 3;
    const int ldso = (c * 12 + hs) * 8;
#pragma unroll
    for (int it = 0; it < 8; ++it) {
      const int s = it * 2 + half;
      const size_t ga = gbase + (size_t)s * SROW + cc * 8;
      *reinterpret_cast<s16x8*>(&Ks[s * 768 + ldso]) =
          *reinterpret_cast<const s16x8*>(&Kg[ga]);
      *reinterpret_cast<s16x8*>(&Vs[s * 768 + ldso]) =
          *reinterpret_cast<const s16x8*>(&Vg[ga]);
    }
  }
  __syncthreads();

  const int h = tid % 12, i = tid / 12;
  const float scale = 0.125f;
  const size_t qoff = gbase + (size_t)i * SROW + h * 64;

  float q[HDc];
#pragma unroll
  for (int c = 0; c < 8; ++c) {
    s16x8 v = *reinterpret_cast<const s16x8*>(&Qg[qoff + c * 8]);
#pragma unroll
    for (int e = 0; e < 8; ++e) q[c * 8 + e] = bf2f(v[e]) * scale;
  }

  float m = -INFINITY, l = 0.f;
  float o[HDc];
#pragma unroll
  for (int d = 0; d < HDc; ++d) o[d] = 0.f;

  for (int j = 0; j <= i; ++j) {
    const short* kr = &Ks[j * 768];
    float s = 0.f;
#pragma unroll
    for (int c = 0; c < 8; ++c) {
      s16x8 kv = *reinterpret_cast<const s16x8*>(kr + (c * 12 + h) * 8);
#pragma unroll
      for (int e = 0; e < 8; ++e) s += q[c * 8 + e] * bf2f(kv[e]);
    }
    float mn   = fmaxf(m, s);
    float corr = __expf(m - mn);
    float pw   = __expf(s - mn);
    l = l * corr + pw;
    const short* vr = &Vs[j * 768];
#pragma unroll
    for (int c = 0; c < 8; ++c) {
      s16x8 vv = *reinterpret_cast<const s16x8*>(vr + (c * 12 + h) * 8);
#pragma unroll
      for (int e = 0; e < 8; ++e)
        o[c * 8 + e] = fmaf(pw, bf2f(vv[e]), o[c * 8 + e] * corr);
    }
    m = mn;
  }
  const float inv = 1.f / l;
  short* op = &Og[qoff];
#pragma unroll
  for (int c = 0; c < 8; ++c) {
    s16x8 v;
#pragma unroll
    for (int e = 0; e < 8; ++e) v[e] = f2bf(o[c * 8 + e] * inv);
    *reinterpret_cast<s16x8*>(op + c * 8) = v;
  }
}

// ---------------------------------------------------------------------------
// LayerNorm over E=768 (bf16 input U): one wave per row, 4 rows per block.
// ---------------------------------------------------------------------------
template<bool OUTBF>
__global__ __launch_bounds__(256)
void layernorm_kernel(const short* __restrict__ U, const float* __restrict__ g,
                      const float* __restrict__ be, void* __restrict__ outv)
{
  const int tid  = threadIdx.x;
  const int lane = tid & 63, w = tid >> 6;
  const size_t row = (size_t)blockIdx.x * 4 + w;
  const short* u = U + row * Ec;

  float x[12];
#pragma unroll
  for (int c = 0; c < 3; ++c) {
    s16x4 v = *reinterpret_cast<const s16x4*>(&u[c * 256 + lane * 4]);
    x[c*4+0] = bf2f(v[0]); x[c*4+1] = bf2f(v[1]);
    x[c*4+2] = bf2f(v[2]); x[c*4+3] = bf2f(v[3]);
  }
  float s = 0.f;
#pragma unroll
  for (int k = 0; k < 12; ++k) s += x[k];
#pragma unroll
  for (int off = 32; off > 0; off >>= 1) s += __shfl_xor(s, off, 64);
  const float mean = s * (1.f / 768.f);

  float vs = 0.f;
#pragma unroll
  for (int k = 0; k < 12; ++k) { float d = x[k] - mean; vs += d * d; }
#pragma unroll
  for (int off = 32; off > 0; off >>= 1) vs += __shfl_xor(vs, off, 64);
  const float rs = rsqrtf(vs * (1.f / 768.f) + 1e-5f);

#pragma unroll
  for (int c = 0; c < 3; ++c) {
    int idx = c * 256 + lane * 4;
    float4 gv = *reinterpret_cast<const float4*>(&g[idx]);
    float4 bv = *reinterpret_cast<const float4*>(&be[idx]);
    float r0 = (x[c*4+0] - mean) * rs * gv.x + bv.x;
    float r1 = (x[c*4+1] - mean) * rs * gv.y + bv.y;
    float r2 = (x[c*4+2] - mean) * rs * gv.z + bv.z;
    float r3 = (x[c*4+3] - mean) * rs * gv.w + bv.w;
    if (OUTBF) {
      short* op = (short*)outv + row * Ec + idx;
      s16x4 v = { f2bf(r0), f2bf(r1), f2bf(r2), f2bf(r3) };
      *reinterpret_cast<s16x4*>(op) = v;
    } else {
      float* op = (float*)outv + row * Ec + idx;
      *reinterpret_cast<float4*>(op) = make_float4(r0, r1, r2, r3);
    }
  }
}

// ---------------------------------------------------------------------------
extern "C" void kernel_launch(void* const* d_in, const int* in_sizes, int n_in,
                              void* d_out, int out_size, void* d_ws, size_t ws_size,
                              hipStream_t stream)
{
  const float* x       = (const float*)d_in[0];
  const float* sa_wqkv = (const float*)d_in[1];
  const float* sa_bqkv = (const float*)d_in[2];
  const float* sa_wo   = (const float*)d_in[3];
  const float* sa_bo   = (const float*)d_in[4];
  const float* sa_g    = (const float*)d_in[5];
  const float* sa_b    = (const float*)d_in[6];
  const float* ta_wqkv = (const float*)d_in[7];
  const float* ta_bqkv = (const float*)d_in[8];
  const float* ta_wo   = (const float*)d_in[9];
  const float* ta_bo   = (const float*)d_in[10];
  const float* ta_g    = (const float*)d_in[11];
  const float* ta_b    = (const float*)d_in[12];
  const float* f_w1    = (const float*)d_in[13];
  const float* f_b1    = (const float*)d_in[14];
  const float* f_w2    = (const float*)d_in[15];
  const float* f_b2    = (const float*)d_in[16];
  const float* f_g     = (const float*)d_in[17];
  const float* f_b     = (const float*)d_in[18];

  float* out = (float*)d_out;

  constexpr size_t EE = (size_t)Ec * Ec;
  constexpr size_t WTOT = 3*EE + EE + 3*EE + EE + 2*(size_t)Ec*FFc;  // 9,437,184
  const size_t need = 12 * ME + 2 * WTOT;
  if (ws_size < need) return;

  short* Xb  = (short*)d_ws;
  short* Qb  = Xb + ME;
  short* Kb  = Qb + ME;
  short* Vtb = Qb + 2 * ME;
  short* Hb  = Qb;              // FFN hidden reuses [1ME,5ME)
  short* U   = Xb + 5 * ME;
  short* Wtb = U + ME;

  short* wt_sa_qkv = Wtb;
  short* wt_sa_wo  = wt_sa_qkv + 3 * EE;
  short* wt_ta_qkv = wt_sa_wo  + EE;
  short* wt_ta_wo  = wt_ta_qkv + 3 * EE;
  short* wt_f_w1   = wt_ta_wo  + EE;
  short* wt_f_w2   = wt_f_w1   + (size_t)Ec * FFc;

  prep_kernel<<<8448, 256, 0, stream>>>(
      x, Xb, sa_wqkv, wt_sa_qkv, sa_wo, wt_sa_wo,
      ta_wqkv, wt_ta_qkv, ta_wo, wt_ta_wo, f_w1, wt_f_w1, f_w2, wt_f_w2);

  // grids: gemm192 -> (M/256)*(N/192); gemm256 -> (M/256)*(N/256)
  const dim3 gQKV((Mrows / 256) * (Ec / 192), 1, 3);      // 256 x3 = 3 rounds
  const dim3 gSQ ((Mrows / 256) * (Ec / 192), 1, 1);      // 256 = 1 round
  const dim3 gFF1((Mrows / 256) * (FFc / 256), 1, 1);     // 768 = 3 rounds

  // ---- Stage A: spatial attention ----
  gemm192_kernel<4><<<gQKV, 512, 0, stream>>>(Xb, wt_sa_qkv, sa_bqkv, nullptr, Qb, Vtb, Mrows, Ec, Ec);
  spatial_attn_kernel<<<dim3(Bc * Sc, Hc, 2), 256, 0, stream>>>(Qb, Kb, Vtb, Qb);
  gemm192_kernel<3><<<gSQ, 512, 0, stream>>>(Qb, wt_sa_wo, sa_bo, Xb, U, nullptr, Mrows, Ec, Ec);
  layernorm_kernel<true><<<Mrows / 4, 256, 0, stream>>>(U, sa_g, sa_b, Xb);

  // ---- Stage B: temporal attention ----
  gemm192_kernel<0><<<gQKV, 512, 0, stream>>>(Xb, wt_ta_qkv, ta_bqkv, nullptr, Qb, nullptr, Mrows, Ec, Ec);
  temporal_attn_kernel<<<Bc * Pc, 192, 0, stream>>>(Qb, Kb, Vtb, Qb);
  gemm192_kernel<3><<<gSQ, 512, 0, stream>>>(Qb, wt_ta_wo, ta_bo, Xb, U, nullptr, Mrows, Ec, Ec);
  layernorm_kernel<true><<<Mrows / 4, 256, 0, stream>>>(U, ta_g, ta_b, Xb);

  // ---- Stage C: FFN ----
  gemm256_kernel<1><<<gFF1, 512, 0, stream>>>(Xb, wt_f_w1, f_b1, nullptr, Hb, nullptr, Mrows, FFc, Ec);
  gemm192_kernel<3><<<gSQ, 512, 0, stream>>>(Hb, wt_f_w2, f_b2, Xb, U, nullptr, Mrows, Ec, FFc);
  layernorm_kernel<false><<<Mrows / 4, 256, 0, stream>>>(U, f_g, f_b, out);
}